// Round 11
// baseline (365.958 us; speedup 1.0000x reference)
//
#include <hip/hip_runtime.h>
#include <hip/hip_bf16.h>
#include <math.h>

#define NN 100000
#define EE 1250000
#define DD 64

typedef __attribute__((ext_vector_type(8))) short short8;
typedef __attribute__((ext_vector_type(4))) float f32x4;

// bf16 helpers (RNE)
__device__ __forceinline__ unsigned short f2b(float f) {
    unsigned u = __float_as_uint(f);
    u += 0x7fffu + ((u >> 16) & 1u);
    return (unsigned short)(u >> 16);
}
__device__ __forceinline__ float b2f(unsigned short h) {
    return __uint_as_float(((unsigned)h) << 16);
}

// ---------------- degree count (int atomics) ----------------
__global__ __launch_bounds__(256) void deg_count(const int* __restrict__ row,
                                                 int* __restrict__ degi, int E) {
    int e = blockIdx.x * 256 + threadIdx.x;
    if (e >= E) return;
    atomicAdd(&degi[row[e]], 1);
}

// ---------------- scan step A ----------------
__global__ __launch_bounds__(256) void scan_a(const int* __restrict__ degi,
                                              int* __restrict__ rowStart,
                                              int* __restrict__ bs, int N) {
    __shared__ int s[256];
    int tid = threadIdx.x;
    int i = blockIdx.x * 256 + tid;
    int v = (i < N) ? degi[i] : 0;
    s[tid] = v;
    __syncthreads();
    for (int off = 1; off < 256; off <<= 1) {
        int t = (tid >= off) ? s[tid - off] : 0;
        __syncthreads();
        s[tid] += t;
        __syncthreads();
    }
    if (i < N) rowStart[i] = s[tid] - v;   // exclusive
    if (tid == 255) bs[blockIdx.x] = s[255];
}

// ---------------- scan step B (1 block) ----------------
__global__ __launch_bounds__(512) void scan_b(int* __restrict__ bs, int nb) {
    __shared__ int s[512];
    int tid = threadIdx.x;
    int v = (tid < nb) ? bs[tid] : 0;
    s[tid] = v;
    __syncthreads();
    for (int off = 1; off < 512; off <<= 1) {
        int t = (tid >= off) ? s[tid - off] : 0;
        __syncthreads();
        s[tid] += t;
        __syncthreads();
    }
    if (tid < nb) bs[tid] = s[tid] - v;    // exclusive
}

// ---------------- scan step C ----------------
__global__ __launch_bounds__(256) void scan_c(int* __restrict__ rowStart,
                                              const int* __restrict__ bs,
                                              int N, int E) {
    int i = blockIdx.x * 256 + threadIdx.x;
    if (i < N) rowStart[i] += bs[blockIdx.x];
    if (i == 0) rowStart[N] = E;
}

// ---------------- dis = deg^-0.5 (deg==0 -> 1) ----------------
__global__ __launch_bounds__(256) void dis_kernel(const int* __restrict__ degi,
                                                  float* __restrict__ dis, int N) {
    int i = blockIdx.x * 256 + threadIdx.x;
    if (i >= N) return;
    int d = degi[i];
    float df = (d == 0) ? 1.0f : (float)d;
    dis[i] = 1.0f / sqrtf(df);
}

// ---------------- degree-bucket sort: rowPerm orders rows by degree ----------
// Purpose: spmm waves own 4 rows; random degrees cost E[max of 4 Poisson]
// ~17 vs mean 12.5 iterations (~35% waste). Sorting rows by degree makes
// trip counts uniform within a wave.
__global__ __launch_bounds__(256) void bucket_hist(const int* __restrict__ degi,
                                                   int* __restrict__ bcnt, int N) {
    __shared__ int l[64];
    int tid = threadIdx.x;
    if (tid < 64) l[tid] = 0;
    __syncthreads();
    int i = blockIdx.x * 256 + tid;
    if (i < N) {
        int b = degi[i]; b = (b > 63) ? 63 : b;
        atomicAdd(&l[b], 1);
    }
    __syncthreads();
    if (tid < 64 && l[tid]) atomicAdd(&bcnt[tid], l[tid]);
}

__global__ void bucket_scan(const int* __restrict__ bcnt, int* __restrict__ gcur) {
    // 1 block, 64 threads: exclusive scan of 64 bucket counts -> cursors
    __shared__ int s[64];
    int tid = threadIdx.x;
    int v = bcnt[tid];
    s[tid] = v;
    __syncthreads();
    for (int off = 1; off < 64; off <<= 1) {
        int t = (tid >= off) ? s[tid - off] : 0;
        __syncthreads();
        s[tid] += t;
        __syncthreads();
    }
    gcur[tid] = s[tid] - v;   // exclusive
}

__global__ __launch_bounds__(256) void row_sort(const int* __restrict__ degi,
                                                int* __restrict__ gcur,
                                                int* __restrict__ rowPerm, int N) {
    __shared__ int lcnt[64], lbase[64], lrank[64];
    int tid = threadIdx.x;
    if (tid < 64) { lcnt[tid] = 0; lrank[tid] = 0; }
    __syncthreads();
    int i = blockIdx.x * 256 + tid;
    int b = -1;
    if (i < N) {
        b = degi[i]; b = (b > 63) ? 63 : b;
        atomicAdd(&lcnt[b], 1);
    }
    __syncthreads();
    if (tid < 64 && lcnt[tid]) lbase[tid] = atomicAdd(&gcur[tid], lcnt[tid]);
    __syncthreads();
    if (i < N) {
        int rme = atomicAdd(&lrank[b], 1);
        rowPerm[lbase[b] + rme] = i;
    }
}

// ---------------- scatter: CSR entries packed to 4 B ----------------
// (col<<15)|valq15. R10 falsified payload-scaling: WRITE ~85 MB is one
// full-line RMW per no-allocate scattered store, payload-independent.
__global__ __launch_bounds__(256) void scatter_kernel(const int* __restrict__ row,
                                                      const int* __restrict__ col,
                                                      const float* __restrict__ w,
                                                      const float* __restrict__ dis,
                                                      const int* __restrict__ rowStart,
                                                      int* __restrict__ cursor,
                                                      unsigned* __restrict__ ev, int E) {
    int e = blockIdx.x * 256 + threadIdx.x;
    if (e >= E) return;
    int r = row[e], c = col[e];
    int pos = rowStart[r] + atomicAdd(&cursor[r], 1);
    float v = dis[r] * w[e] * dis[c];
    int vq = (int)(v * 32768.0f + 0.5f);
    vq = (vq > 32767) ? 32767 : vq;
    ev[pos] = ((unsigned)c << 15) | (unsigned)vq;
}

// ---------------- scalar coefficients ----------------
__global__ void coef_kernel(const float* __restrict__ ap, float* __restrict__ coef) {
    if (threadIdx.x != 0 || blockIdx.x != 0) return;
    const float a = 1.0f, b = 1.0f, l = -1.0f, r = 1.0f;
    float als[3];
    als[0] = tanhf(ap[0]);
    als[1] = tanhf(ap[1]);
    als[2] = tanhf(ap[2]);
    float coef1 = (a - b) * 0.5f - (a + b + 2.0f) * 0.5f * ((l + r) / (r - l));
    float coef2 = (a + b + 2.0f) / (r - l);
    coef[0] = als[0] * coef1;
    coef[1] = als[0] * coef2;
    for (int L = 2; L <= 3; ++L) {
        float Lf = (float)L;
        float coef_l     = 2.0f * Lf * (Lf + a + b) * (2.0f * Lf - 2.0f + a + b);
        float coef_lm1_1 = (2.0f * Lf + a + b - 1.0f) * (2.0f * Lf + a + b) * (2.0f * Lf + a + b - 2.0f);
        float coef_lm1_2 = (2.0f * Lf + a + b - 1.0f) * (a * a - b * b);
        float coef_lm2   = 2.0f * (Lf - 1.0f + a) * (Lf - 1.0f + b) * (2.0f * Lf + a + b);
        float tmp1   = als[L - 1] * (coef_lm1_1 / coef_l);
        float tmp2   = als[L - 1] * (coef_lm1_2 / coef_l);
        float tmp3   = als[L - 1] * als[L - 2] * (coef_lm2 / coef_l);
        float tmp1_2 = tmp1 * (2.0f / (r - l));
        float tmp2_2 = tmp1 * ((r + l) / (r - l)) + tmp2;
        int base = 2 + (L - 2) * 3;
        coef[base + 0] = tmp1_2;
        coef[base + 1] = tmp2_2;
        coef[base + 2] = tmp3;
    }
}

// ---------------- fp32 -> bf16 copy ----------------
__global__ __launch_bounds__(256) void tobf16(const float4* __restrict__ in,
                                              ushort4* __restrict__ outb, int n4) {
    int i = blockIdx.x * 256 + threadIdx.x;
    if (i >= n4) return;
    float4 v = in[i];
    ushort4 o;
    o.x = f2b(v.x); o.y = f2b(v.y); o.z = f2b(v.z); o.w = f2b(v.w);
    outb[i] = o;
}

// ---------------- W transpose to bf16 [n][k] (B^T layout for MFMA) ----------
__global__ __launch_bounds__(256) void wt_kernel(const float* __restrict__ W,
                                                 unsigned short* __restrict__ Wt) {
    int idx = blockIdx.x * 256 + threadIdx.x;   // 0..16383
    int n = idx >> 8, k = idx & 255;
    Wt[idx] = f2b(W[k * 64 + n]);
}

// ---------------- fused CSR SpMM + combine, degree-sorted row order ---------
// 16 lanes per row pr=rowPerm[r]: uniform trips within a wave. fp32 accum.
// MODE 0: out = c0*m1 + c1*Ax; MODE 1: out = c0*Ax - c1*m1 - c2*m2
#define VSCL (1.0f / 32768.0f)
template <int MODE>
__global__ __launch_bounds__(256) void spmm_fused(const int* __restrict__ rowStart,
                                                  const int* __restrict__ rowPerm,
                                                  const unsigned* __restrict__ ev,
                                                  const ushort4* __restrict__ hb,
                                                  const ushort4* __restrict__ xm1,
                                                  const ushort4* __restrict__ xm2,
                                                  ushort4* __restrict__ outb,
                                                  const float* __restrict__ coef,
                                                  int cbase, int N) {
    int t = blockIdx.x * 256 + threadIdx.x;
    int r = t >> 4;
    if (r >= N) return;
    int q = t & 15;
    int pr = rowPerm[r];
    int s0 = rowStart[pr];
    int s1 = rowStart[pr + 1];
    float4 acc = make_float4(0.f, 0.f, 0.f, 0.f);
    int j = s0;
    for (; j + 3 < s1; j += 4) {
        unsigned u0 = ev[j];
        unsigned u1 = ev[j + 1];
        unsigned u2 = ev[j + 2];
        unsigned u3 = ev[j + 3];
        ushort4 h0 = hb[(size_t)(u0 >> 15) * 16 + q];
        ushort4 h1 = hb[(size_t)(u1 >> 15) * 16 + q];
        ushort4 h2 = hb[(size_t)(u2 >> 15) * 16 + q];
        ushort4 h3 = hb[(size_t)(u3 >> 15) * 16 + q];
        float v0 = (float)(u0 & 0x7fffu) * VSCL;
        float v1 = (float)(u1 & 0x7fffu) * VSCL;
        float v2 = (float)(u2 & 0x7fffu) * VSCL;
        float v3 = (float)(u3 & 0x7fffu) * VSCL;
        acc.x += v0 * b2f(h0.x) + v1 * b2f(h1.x) + v2 * b2f(h2.x) + v3 * b2f(h3.x);
        acc.y += v0 * b2f(h0.y) + v1 * b2f(h1.y) + v2 * b2f(h2.y) + v3 * b2f(h3.y);
        acc.z += v0 * b2f(h0.z) + v1 * b2f(h1.z) + v2 * b2f(h2.z) + v3 * b2f(h3.z);
        acc.w += v0 * b2f(h0.w) + v1 * b2f(h1.w) + v2 * b2f(h2.w) + v3 * b2f(h3.w);
    }
    for (; j < s1; ++j) {
        unsigned u0 = ev[j];
        ushort4 h0 = hb[(size_t)(u0 >> 15) * 16 + q];
        float v0 = (float)(u0 & 0x7fffu) * VSCL;
        acc.x += v0 * b2f(h0.x);
        acc.y += v0 * b2f(h0.y);
        acc.z += v0 * b2f(h0.z);
        acc.w += v0 * b2f(h0.w);
    }
    size_t oi = (size_t)pr * 16 + q;
    float4 o;
    if (MODE == 0) {
        float c0 = coef[cbase], c1 = coef[cbase + 1];
        ushort4 m1 = xm1[oi];
        o.x = c0 * b2f(m1.x) + c1 * acc.x;
        o.y = c0 * b2f(m1.y) + c1 * acc.y;
        o.z = c0 * b2f(m1.z) + c1 * acc.z;
        o.w = c0 * b2f(m1.w) + c1 * acc.w;
    } else {
        float c0 = coef[cbase], c1 = coef[cbase + 1], c2 = coef[cbase + 2];
        ushort4 m1 = xm1[oi];
        ushort4 m2 = xm2[oi];
        o.x = c0 * acc.x - c1 * b2f(m1.x) - c2 * b2f(m2.x);
        o.y = c0 * acc.y - c1 * b2f(m1.y) - c2 * b2f(m2.y);
        o.z = c0 * acc.z - c1 * b2f(m1.z) - c2 * b2f(m2.z);
        o.w = c0 * acc.w - c1 * b2f(m1.w) - c2 * b2f(m2.w);
    }
    ushort4 ob;
    ob.x = f2b(o.x); ob.y = f2b(o.y); ob.z = f2b(o.z); ob.w = f2b(o.w);
    outb[oi] = ob;
}

// ---------------- final GEMM via MFMA: out = [x|A|B|C] @ W + bias -----------
// Block = 256 thr (4 waves) = 64 node rows. All four X segments bf16 in ws.
// LDS stride 264 bf16 (528 B): A-frag b128 reads 2 lanes/bank-quad = free.
// Wt = pre-transposed bf16 [n][k] (B^T) read from global (L1-resident).
// Layouts (verified): A[m=lane&15][k=quad*8+j]; D: col=lane&15, row=quad*4+reg.
#define XLD 264
__global__ __launch_bounds__(256) void final_gemm_mfma(
        const ushort4* __restrict__ x0,
        const ushort4* __restrict__ x1,
        const ushort4* __restrict__ x2,
        const ushort4* __restrict__ x3,
        const unsigned short* __restrict__ Wt,
        const float* __restrict__ bias,
        float* __restrict__ out) {
    __shared__ unsigned short Xb[64 * XLD];
    const int tid = threadIdx.x;
    const int lane = tid & 63;
    const int w = tid >> 6;
    const int m = lane & 15;
    const int quad = lane >> 4;
    const int n0 = (int)blockIdx.x * 64;

    #pragma unroll 1
    for (int seg = 0; seg < 4; ++seg) {
        const ushort4* p = (seg == 0) ? x0 : (seg == 1) ? x1 : (seg == 2) ? x2 : x3;
        #pragma unroll
        for (int j = 0; j < 4; ++j) {
            int idx = tid + 256 * j;          // 0..1023
            int r = idx >> 4, c4 = idx & 15;
            int gr = n0 + r;
            ushort4 hv = (gr < NN) ? p[(size_t)gr * 16 + c4] : make_ushort4(0, 0, 0, 0);
            *(ushort4*)&Xb[r * XLD + seg * 64 + c4 * 4] = hv;
        }
    }
    __syncthreads();

    f32x4 acc[4];
    #pragma unroll
    for (int nt = 0; nt < 4; ++nt) acc[nt] = (f32x4){0.f, 0.f, 0.f, 0.f};

    #pragma unroll 1
    for (int ks = 0; ks < 8; ++ks) {
        short8 af = *(const short8*)&Xb[(16 * w + m) * XLD + ks * 32 + quad * 8];
        #pragma unroll
        for (int nt = 0; nt < 4; ++nt) {
            short8 bf = *(const short8*)&Wt[(nt * 16 + m) * 256 + ks * 32 + quad * 8];
            acc[nt] = __builtin_amdgcn_mfma_f32_16x16x32_bf16(af, bf, acc[nt], 0, 0, 0);
        }
    }

    #pragma unroll
    for (int nt = 0; nt < 4; ++nt) {
        float bv = bias[nt * 16 + m];
        #pragma unroll
        for (int rg = 0; rg < 4; ++rg) {
            int node = n0 + 16 * w + quad * 4 + rg;
            if (node < NN) out[(size_t)node * 64 + nt * 16 + m] = acc[nt][rg] + bv;
        }
    }
}

extern "C" void kernel_launch(void* const* d_in, const int* in_sizes, int n_in,
                              void* d_out, int out_size, void* d_ws, size_t ws_size,
                              hipStream_t stream) {
    const float* x  = (const float*)d_in[0];
    const int*   ei = (const int*)d_in[1];
    const float* ew = (const float*)d_in[2];
    const float* ap = (const float*)d_in[3];
    const float* lw = (const float*)d_in[4];
    const float* lb = (const float*)d_in[5];
    float* out = (float*)d_out;

    const int N = NN, E = EE;
    const int ND = N * DD;

    const int* row = ei;
    const int* col = ei + E;

    // workspace: xb | Ab | Bb | Cb (bf16) | ev(4B) | small
    char* ws = (char*)d_ws;
    ushort4* xb = (ushort4*)ws;                            // 12.8 MB
    ushort4* Ab = (ushort4*)(ws + (size_t)ND * 2);         // 12.8 MB
    ushort4* Bb = (ushort4*)(ws + (size_t)ND * 4);         // 12.8 MB
    ushort4* Cb = (ushort4*)(ws + (size_t)ND * 6);         // 12.8 MB
    unsigned* ev = (unsigned*)(ws + (size_t)ND * 8);       // 5 MB
    char* sm    = ws + (size_t)ND * 8 + (size_t)E * 4;
    float* coef     = (float*)sm;                          // 256 B
    float* dis      = (float*)(sm + 256);                  // N floats
    int*   degi     = (int*)(sm + 256 + (size_t)N * 4);    // N ints (also cursor)
    int*   rowStart = (int*)(sm + 256 + (size_t)N * 8);    // N+1 ints
    int*   bs       = (int*)(sm + 256 + (size_t)N * 12 + 64);       // 512 ints
    unsigned short* Wt = (unsigned short*)(sm + 256 + (size_t)N * 12 + 64 + 4096); // 32 KB
    char* sm2 = sm + 256 + (size_t)N * 12 + 64 + 4096 + 32768;
    int* rowPerm = (int*)sm2;                              // N ints
    int* bcnt    = (int*)(sm2 + (size_t)N * 4);            // 64 ints
    int* gcur    = (int*)(sm2 + (size_t)N * 4 + 256);      // 64 ints

    const int gridE  = (E + 255) / 256;      // 4883
    const int gridN  = (N + 255) / 256;      // 391
    const int gridSp = (N * 16) / 256;       // 6250 exact
    const int gridCv = (ND / 4) / 256;       // 6250 exact
    const int gridG  = (N + 63) / 64;        // 1563

    // ---- CSR build + degree sort ----
    hipMemsetAsync(degi, 0, (size_t)N * 4, stream);
    hipMemsetAsync(bcnt, 0, 256, stream);
    deg_count<<<gridE, 256, 0, stream>>>(row, degi, E);
    coef_kernel<<<1, 64, 0, stream>>>(ap, coef);
    wt_kernel<<<64, 256, 0, stream>>>(lw, Wt);
    bucket_hist<<<gridN, 256, 0, stream>>>(degi, bcnt, N);
    bucket_scan<<<1, 64, 0, stream>>>(bcnt, gcur);
    row_sort<<<gridN, 256, 0, stream>>>(degi, gcur, rowPerm, N);
    scan_a<<<gridN, 256, 0, stream>>>(degi, rowStart, bs, N);
    scan_b<<<1, 512, 0, stream>>>(bs, gridN);
    scan_c<<<gridN, 256, 0, stream>>>(rowStart, bs, N, E);
    dis_kernel<<<gridN, 256, 0, stream>>>(degi, dis, N);
    hipMemsetAsync(degi, 0, (size_t)N * 4, stream);        // reuse as cursor
    scatter_kernel<<<gridE, 256, 0, stream>>>(row, col, ew, dis, rowStart, degi, ev, E);

    // ---- bf16 copy of x ----
    tobf16<<<gridCv, 256, 0, stream>>>((const float4*)x, xb, ND / 4);

    // ---- L=1: Ab = c0*x + c1*(adj@x) ----
    spmm_fused<0><<<gridSp, 256, 0, stream>>>(rowStart, rowPerm, ev, xb, xb, xb,
                                              Ab, coef, 0, N);
    // ---- L=2: Bb = c0*(adj@A) - c1*A - c2*x ----
    spmm_fused<1><<<gridSp, 256, 0, stream>>>(rowStart, rowPerm, ev, Ab, Ab, xb,
                                              Bb, coef, 2, N);
    // ---- L=3: Cb = c0*(adj@B) - c1*B - c2*A ----
    spmm_fused<1><<<gridSp, 256, 0, stream>>>(rowStart, rowPerm, ev, Bb, Bb, Ab,
                                              Cb, coef, 5, N);

    // ---- out = [x | A | B | C] @ W + b (MFMA) ----
    final_gemm_mfma<<<gridG, 256, 0, stream>>>(xb, Ab, Bb, Cb, Wt, lb, out);
}